// Round 16
// baseline (73.731 us; speedup 1.0000x reference)
//
#include <hip/hip_runtime.h>
#include <float.h>
#include <math.h>

#define EPS 1e-6f

typedef __attribute__((ext_vector_type(8))) short short8;   // 8 bf16 = 4 VGPR
typedef __attribute__((ext_vector_type(4))) float f32x4;

constexpr int Nn = 8192;   // B*H*W
constexpr int Dd = 64;
constexpr int Kk = 8192;
constexpr int PLANE = Nn * Dd;
constexpr int KSPLIT = 16;
constexpr int KPB = Kk / KSPLIT;          // 512 codewords per strip
constexpr int NT = KPB / 16;              // 32 tiles per strip
constexpr int NPAIR = NT / 2;             // 16 tile-pairs per strip
constexpr int TILE_USH = 4096;            // padded tile: 7 frags*512 + 512 pad
constexpr int PAIR_BYTES = 2 * TILE_USH * 2;  // 16384 B per pair

// exact 3-way bf16 split: v == f(h1)+f(h2)+f(h3) (24 mantissa bits, lossless)
__device__ __forceinline__ void split3(float v, unsigned short& h1, unsigned short& h2, unsigned short& h3) {
    unsigned u = __float_as_uint(v);
    h1 = (unsigned short)(u >> 16);
    float r1 = v - __uint_as_float((unsigned)h1 << 16);
    h2 = (unsigned short)(__float_as_uint(r1) >> 16);
    float r2 = r1 - __uint_as_float((unsigned)h2 << 16);
    h3 = (unsigned short)(__float_as_uint(r2) >> 16);
}

// monotone float -> uint mapping (total order preserved)
__device__ __forceinline__ unsigned sortable(float v) {
    unsigned u = __float_as_uint(v);
    return (u & 0x80000000u) ? ~u : (u | 0x80000000u);
}
__device__ __forceinline__ float unsortable(unsigned s) {
    unsigned u = (s & 0x80000000u) ? (s & 0x7FFFFFFFu) : ~s;
    return __uint_as_float(u);
}

typedef __attribute__((address_space(3))) unsigned int lds_u32_t;
typedef __attribute__((address_space(1))) unsigned int glb_u32_t;
__device__ __forceinline__ void gload_lds16(const void* g, void* l) {
    __builtin_amdgcn_global_load_lds((const glb_u32_t*)g, (lds_u32_t*)l, 16, 0, 0);
}

// ---- prep: 128 blocks x 128 threads (2x CU coverage vs 64x256).
// blocks 0..63: e -> es_t frags + en2h + et. blocks 64..127: x -> xs + xn2
// + packed re-init (deterministic per call). ----
__global__ __launch_bounds__(128) void prep_kernel(
    const float* __restrict__ e, const float* __restrict__ x,
    unsigned short* __restrict__ es_t, float* __restrict__ en2h,
    float* __restrict__ et,
    unsigned short* __restrict__ xs, float* __restrict__ xn2,
    unsigned long long* __restrict__ packed)
{
    const int tid = threadIdx.x;
    if (blockIdx.x < 64) {
        const int k = blockIdx.x * 128 + tid;
        const int t = k >> 4, l15 = k & 15;
        unsigned short* tb = es_t + (size_t)t * TILE_USH;
        float s = 0.f;
        #pragma unroll
        for (int c = 0; c < 8; ++c) {          // c = ks*4 + kg ; d = c*8 + j
            const int ks = c >> 2, kg = c & 3;
            short8 h1v, h2v, h3v;
            float fv[8];
            #pragma unroll
            for (int j = 0; j < 8; ++j) {
                float v = e[(c * 8 + j) * Kk + k];
                fv[j] = v;
                s = fmaf(v, v, s);
                unsigned short h1, h2, h3; split3(v, h1, h2, h3);
                h1v[j] = (short)h1; h2v[j] = (short)h2; h3v[j] = (short)h3;
            }
            const int lofs = (kg * 16 + l15) * 8;
            *(short8*)(tb + (0 * 2 + ks) * 512 + lofs) = h1v;
            *(short8*)(tb + (1 * 2 + ks) * 512 + lofs) = h2v;
            *(short8*)(tb + (2 * 2 + ks) * 512 + lofs) = h3v;
            *(float4*)(et + (size_t)k * Dd + c * 8)     = *(float4*)&fv[0];
            *(float4*)(et + (size_t)k * Dd + c * 8 + 4) = *(float4*)&fv[4];
        }
        // frag 6: en = 0.5||e||^2 split into bf16x3 at k-slots 0..2 (kg==0 rows)
        unsigned short s1, s2, s3; split3(0.5f * s, s1, s2, s3);
        short8 env = {(short)s1, (short)s2, (short)s3, 0, 0, 0, 0, 0};
        short8 zz  = {0, 0, 0, 0, 0, 0, 0, 0};
        *(short8*)(tb + 6 * 512 + l15 * 8) = env;             // kg = 0
        *(short8*)(tb + 6 * 512 + (16 + l15) * 8) = zz;       // kg = 1..3: zero
        *(short8*)(tb + 6 * 512 + (32 + l15) * 8) = zz;
        *(short8*)(tb + 6 * 512 + (48 + l15) * 8) = zz;
        en2h[k] = 0.5f * s;
    } else {
        const int p = (blockIdx.x - 64) * 128 + tid;
        const int b = p >> 10, hw = p & 1023;
        packed[p] = ~0ull;                    // re-init argmin cell every call
        float s = 0.f;
        #pragma unroll
        for (int c = 0; c < 8; ++c) {
            short8 h1v, h2v, h3v;
            #pragma unroll
            for (int j = 0; j < 8; ++j) {
                float v = x[(b * Dd + c * 8 + j) * 1024 + hw];
                s = fmaf(v, v, s);
                unsigned short h1, h2, h3; split3(-v, h1, h2, h3);   // negated
                h1v[j] = (short)h1; h2v[j] = (short)h2; h3v[j] = (short)h3;
            }
            *(short8*)(xs + (size_t)p * Dd + c * 8) = h1v;
            *(short8*)(xs + PLANE + (size_t)p * Dd + c * 8) = h2v;
            *(short8*)(xs + 2 * PLANE + (size_t)p * Dd + c * 8) = h3v;
        }
        xn2[p] = s;
    }
}

// one 16-codeword tile: 1 en-MFMA + 24 product MFMAs + argmin.
// Within-lane idx tiebreak (s==bv -> smaller idx) makes the result
// independent of tile visiting order (needed for the ring iteration).
__device__ __forceinline__ void tile_compute(
    const short8 (&a)[2][3][2], const short8 a_ones, const short8 (&b)[7],
    int nb, int l15, float (&bv)[2][4], int (&bi)[2][4])
{
    const f32x4 zero = {0.f, 0.f, 0.f, 0.f};
    f32x4 acc_en = __builtin_amdgcn_mfma_f32_16x16x32_bf16(a_ones, b[6], zero, 0, 0, 0);
    f32x4 acc[2][2];
    acc[0][0] = acc_en; acc[1][0] = acc_en;
    acc[0][1] = zero;   acc[1][1] = zero;
    #define PROD(sx, se) \
        acc[0][0] = __builtin_amdgcn_mfma_f32_16x16x32_bf16(a[0][sx][0], b[(se)*2+0], acc[0][0], 0,0,0); \
        acc[1][0] = __builtin_amdgcn_mfma_f32_16x16x32_bf16(a[1][sx][0], b[(se)*2+0], acc[1][0], 0,0,0); \
        acc[0][1] = __builtin_amdgcn_mfma_f32_16x16x32_bf16(a[0][sx][1], b[(se)*2+1], acc[0][1], 0,0,0); \
        acc[1][1] = __builtin_amdgcn_mfma_f32_16x16x32_bf16(a[1][sx][1], b[(se)*2+1], acc[1][1], 0,0,0);
    PROD(0,0) PROD(0,1) PROD(1,0) PROD(0,2) PROD(1,1) PROD(2,0)
    #undef PROD
    #pragma unroll
    for (int mi = 0; mi < 2; ++mi)
        #pragma unroll
        for (int j = 0; j < 4; ++j) {
            float s = acc[mi][0][j] + acc[mi][1][j];   // en - x.e
            int idx = nb + l15;
            if (s < bv[mi][j] || (s == bv[mi][j] && idx < bi[mi][j])) {
                bv[mi][j] = s; bi[mi][j] = idx;
            }
        }
}

// R12 cadence + RING iteration (per-block start offset decorrelates the
// phases of co-resident blocks -> MFMA bursts interleave instead of collide)
// + T5 setprio around the MFMA cluster. Epilogue: packed u64 atomicMin.
// NOTE: do NOT set a tight min-waves hint (R6: VGPR capped to 48 -> spill).
__global__ __launch_bounds__(256, 2) void dist_mfma(
    const unsigned short* __restrict__ xs, const unsigned short* __restrict__ es_t,
    unsigned long long* __restrict__ packed)
{
    __shared__ __align__(16) unsigned short sB[2][2 * TILE_USH];  // 2 x 16 KB

    const int tid = threadIdx.x;
    const int w = tid >> 6, lane = tid & 63;
    const int l15 = lane & 15, kg = lane >> 4;
    const int m0 = blockIdx.x * 128 + w * 32;
    const int t0 = blockIdx.y * NT;
    const int pr0 = t0 / 2;

    short8 a[2][3][2];
    #pragma unroll
    for (int mi = 0; mi < 2; ++mi) {
        const unsigned short* xp = xs + (size_t)(m0 + mi * 16 + l15) * Dd + kg * 8;
        #pragma unroll
        for (int s = 0; s < 3; ++s)
            #pragma unroll
            for (int ks = 0; ks < 2; ++ks)
                a[mi][s][ks] = *(const short8*)(xp + s * PLANE + ks * 32);
    }
    const short8 a_ones = (kg == 0)
        ? short8{(short)0x3F80, (short)0x3F80, (short)0x3F80, 0, 0, 0, 0, 0}
        : short8{0, 0, 0, 0, 0, 0, 0, 0};

    float bv[2][4]; int bi[2][4];
    #pragma unroll
    for (int mi = 0; mi < 2; ++mi)
        #pragma unroll
        for (int j = 0; j < 4; ++j) { bv[mi][j] = FLT_MAX; bi[mi][j] = 0; }

    #define STAGE_PAIR(buf, pi) { \
        const char* gb_ = (const char*)es_t + (size_t)(pi) * PAIR_BYTES; \
        char* lb_ = (char*)&sB[buf][0]; \
        _Pragma("unroll") \
        for (int r_ = 0; r_ < 4; ++r_) { \
            const int off_ = r_ * 4096 + w * 1024; \
            gload_lds16(gb_ + off_ + lane * 16, lb_ + off_); } }

    // ring start: decorrelate co-resident blocks' phases
    const int start = (blockIdx.x * 5) & (NPAIR - 1);

    STAGE_PAIR(0, pr0 + start)
    asm volatile("s_waitcnt vmcnt(0)" ::: "memory");
    asm volatile("s_barrier" ::: "memory");

    #pragma unroll 1
    for (int it = 0; it < NPAIR; ++it) {
        const int pp = (start + it) & (NPAIR - 1);
        const int pn = (start + it + 1) & (NPAIR - 1);   // wraps: uniform count
        const int cur = it & 1;
        STAGE_PAIR(cur ^ 1, pr0 + pn)
        asm volatile("s_waitcnt vmcnt(4)" ::: "memory");   // pair pp staged
        asm volatile("s_barrier" ::: "memory");            // buf[cur] ready

        short8 bf0[7], bf1[7];
        const unsigned short* lb = &sB[cur][lane * 8];
        #pragma unroll
        for (int f = 0; f < 7; ++f) bf0[f] = *(const short8*)(lb + f * 512);
        #pragma unroll
        for (int f = 0; f < 7; ++f) bf1[f] = *(const short8*)(lb + TILE_USH + f * 512);
        asm volatile("s_waitcnt lgkmcnt(0)" ::: "memory");
        asm volatile("s_barrier" ::: "memory");            // buf[cur] free

        const int ti = t0 + pp * 2;
        __builtin_amdgcn_s_setprio(1);
        tile_compute(a, a_ones, bf0, ti * 16, l15, bv, bi);
        tile_compute(a, a_ones, bf1, ti * 16 + 16, l15, bv, bi);
        __builtin_amdgcn_s_setprio(0);
    }

    #pragma unroll
    for (int m = 1; m < 16; m <<= 1) {
        #pragma unroll
        for (int mi = 0; mi < 2; ++mi)
            #pragma unroll
            for (int j = 0; j < 4; ++j) {
                float ov = __shfl_xor(bv[mi][j], m, 64);
                int   oi = __shfl_xor(bi[mi][j], m, 64);
                if (ov < bv[mi][j] || (ov == bv[mi][j] && oi < bi[mi][j])) {
                    bv[mi][j] = ov; bi[mi][j] = oi;
                }
            }
    }
    if (l15 == 0) {
        #pragma unroll
        for (int mi = 0; mi < 2; ++mi)
            #pragma unroll
            for (int j = 0; j < 4; ++j) {
                int pix = m0 + mi * 16 + kg * 4 + j;
                unsigned long long pk =
                    ((unsigned long long)sortable(bv[mi][j]) << 32) | (unsigned)bi[mi][j];
                atomicMin(&packed[pix], pk);
            }
    }
}

// ---- apply: unpack winner, coefficients inline, stream qd/q; ind at y==0 ----
// grid (32, 8): 256 pixels per block, 8 d's per blockIdx.y
__global__ __launch_bounds__(256) void apply_kernel(
    const float* __restrict__ x, const float* __restrict__ et,
    const float* __restrict__ en2h, const float* __restrict__ xn2,
    const unsigned long long* __restrict__ packed,
    float* __restrict__ out_qd, float* __restrict__ out_q, float* __restrict__ out_ind)
{
    const int p = blockIdx.x * 256 + threadIdx.x;
    const unsigned long long pk = packed[p];
    const int bii = (int)(pk & 0xFFFFFFFFu);
    const float bvv = unsortable((unsigned)(pk >> 32));
    if (blockIdx.y == 0) out_ind[p] = (float)bii;

    float sx2 = xn2[p];
    float enh = en2h[bii];
    float sq2 = 2.f * enh;            // ||q||^2
    float sxq = enh - bvv;            // x.q recovered from winning score
    float ne = sqrtf(sx2), nq = sqrtf(sq2);
    float inv_e = 1.f / (ne + EPS), inv_q = 1.f / (nq + EPS);
    float lmbda = (nq + EPS) * inv_e;
    float ehat_dot_e = sx2 * inv_e;
    float rn2 = sx2 * inv_e * inv_e + 2.f * sxq * inv_e * inv_q + sq2 * inv_q * inv_q;
    float inv_r = rsqrtf(rn2);
    float rde = (sx2 * inv_e + sxq * inv_q) * inv_r;
    float cx = lmbda * (1.f - 2.f * rde * inv_r * inv_e);
    float cq = 2.f * lmbda * inv_q * (ehat_dot_e - rde * inv_r);

    const int b = p >> 10, hw = p & 1023;
    const int d0 = blockIdx.y * 8;
    const float* xb = x + (b * Dd + d0) * 1024 + hw;
    const float* er = et + (size_t)bii * Dd + d0;
    float* qd_b = out_qd + (b * Dd + d0) * 1024 + hw;
    float* q_b  = out_q  + (b * Dd + d0) * 1024 + hw;
    #pragma unroll
    for (int dv = 0; dv < 2; ++dv) {
        float4 q4 = *(const float4*)(er + dv * 4);
        #pragma unroll
        for (int jj = 0; jj < 4; ++jj) {
            int d = dv * 4 + jj;
            float xv = xb[d * 1024];
            float qv = ((const float*)&q4)[jj];
            qd_b[d * 1024] = cx * xv + cq * qv;
            q_b[d * 1024]  = qv;
        }
    }
}

extern "C" void kernel_launch(void* const* d_in, const int* in_sizes, int n_in,
                              void* d_out, int out_size, void* d_ws, size_t ws_size,
                              hipStream_t stream) {
    const float* x = (const float*)d_in[0];   // (8,64,32,32)
    const float* e = (const float*)d_in[1];   // (64,8192)
    float* out = (float*)d_out;
    float* out_qd  = out;
    float* out_q   = out + Nn * Dd;
    float* out_ind = out + 2 * Nn * Dd;

    unsigned short* xs   = (unsigned short*)d_ws;          // 3*PLANE ushort (3 MB)
    unsigned short* es_t = xs + 3 * PLANE;                 // 512*4096 ushort (4 MB)
    float* et   = (float*)(es_t + (size_t)(Kk / 16) * TILE_USH);  // Kk*Dd f32 (2 MB)
    float* en2h = et + (size_t)Kk * Dd;                    // Kk f32
    float* xn2  = en2h + Kk;                               // Nn f32
    unsigned long long* packed = (unsigned long long*)(xn2 + Nn);  // Nn u64 (64 KB)

    prep_kernel<<<128, 128, 0, stream>>>(e, x, es_t, en2h, et, xs, xn2, packed);
    dist_mfma<<<dim3(Nn / 128, KSPLIT), 256, 0, stream>>>(xs, es_t, packed);
    apply_kernel<<<dim3(Nn / 256, 8), 256, 0, stream>>>(x, et, en2h, xn2, packed,
                                                        out_qd, out_q, out_ind);
}

// Round 17
// 61.218 us; speedup vs baseline: 1.2044x; 1.2044x over previous
//
#include <hip/hip_runtime.h>
#include <float.h>
#include <math.h>

#define EPS 1e-6f

typedef __attribute__((ext_vector_type(8))) short short8;   // 8 bf16 = 4 VGPR
typedef __attribute__((ext_vector_type(4))) float f32x4;

constexpr int Nn = 8192;   // B*H*W
constexpr int Dd = 64;
constexpr int Kk = 8192;
constexpr int PLANE = Nn * Dd;
constexpr int KSPLIT = 16;
constexpr int KPB = Kk / KSPLIT;          // 512 codewords per strip
constexpr int NT = KPB / 16;              // 32 tiles per strip
constexpr int NPAIR = NT / 2;             // 16 tile-pairs per strip
constexpr int TILE_USH = 4096;            // padded tile: 7 frags*512 + 512 pad
constexpr int PAIR_BYTES = 2 * TILE_USH * 2;  // 16384 B per pair

// exact 3-way bf16 split: v == f(h1)+f(h2)+f(h3) (24 mantissa bits, lossless)
__device__ __forceinline__ void split3(float v, unsigned short& h1, unsigned short& h2, unsigned short& h3) {
    unsigned u = __float_as_uint(v);
    h1 = (unsigned short)(u >> 16);
    float r1 = v - __uint_as_float((unsigned)h1 << 16);
    h2 = (unsigned short)(__float_as_uint(r1) >> 16);
    float r2 = r1 - __uint_as_float((unsigned)h2 << 16);
    h3 = (unsigned short)(__float_as_uint(r2) >> 16);
}

// monotone float -> uint mapping (total order preserved)
__device__ __forceinline__ unsigned sortable(float v) {
    unsigned u = __float_as_uint(v);
    return (u & 0x80000000u) ? ~u : (u | 0x80000000u);
}
__device__ __forceinline__ float unsortable(unsigned s) {
    unsigned u = (s & 0x80000000u) ? (s & 0x7FFFFFFFu) : ~s;
    return __uint_as_float(u);
}

typedef __attribute__((address_space(3))) unsigned int lds_u32_t;
typedef __attribute__((address_space(1))) unsigned int glb_u32_t;
__device__ __forceinline__ void gload_lds16(const void* g, void* l) {
    __builtin_amdgcn_global_load_lds((const glb_u32_t*)g, (lds_u32_t*)l, 16, 0, 0);
}

// ---- prep: 128 blocks x 128 threads (2x CU coverage vs 64x256).
// blocks 0..63: e -> es_t frags + en2h + et. blocks 64..127: x -> xs + xn2
// + packed re-init (deterministic per call). ----
__global__ __launch_bounds__(128) void prep_kernel(
    const float* __restrict__ e, const float* __restrict__ x,
    unsigned short* __restrict__ es_t, float* __restrict__ en2h,
    float* __restrict__ et,
    unsigned short* __restrict__ xs, float* __restrict__ xn2,
    unsigned long long* __restrict__ packed)
{
    const int tid = threadIdx.x;
    if (blockIdx.x < 64) {
        const int k = blockIdx.x * 128 + tid;
        const int t = k >> 4, l15 = k & 15;
        unsigned short* tb = es_t + (size_t)t * TILE_USH;
        float s = 0.f;
        #pragma unroll
        for (int c = 0; c < 8; ++c) {          // c = ks*4 + kg ; d = c*8 + j
            const int ks = c >> 2, kg = c & 3;
            short8 h1v, h2v, h3v;
            float fv[8];
            #pragma unroll
            for (int j = 0; j < 8; ++j) {
                float v = e[(c * 8 + j) * Kk + k];
                fv[j] = v;
                s = fmaf(v, v, s);
                unsigned short h1, h2, h3; split3(v, h1, h2, h3);
                h1v[j] = (short)h1; h2v[j] = (short)h2; h3v[j] = (short)h3;
            }
            const int lofs = (kg * 16 + l15) * 8;
            *(short8*)(tb + (0 * 2 + ks) * 512 + lofs) = h1v;
            *(short8*)(tb + (1 * 2 + ks) * 512 + lofs) = h2v;
            *(short8*)(tb + (2 * 2 + ks) * 512 + lofs) = h3v;
            *(float4*)(et + (size_t)k * Dd + c * 8)     = *(float4*)&fv[0];
            *(float4*)(et + (size_t)k * Dd + c * 8 + 4) = *(float4*)&fv[4];
        }
        // frag 6: en = 0.5||e||^2 split into bf16x3 at k-slots 0..2 (kg==0 rows)
        unsigned short s1, s2, s3; split3(0.5f * s, s1, s2, s3);
        short8 env = {(short)s1, (short)s2, (short)s3, 0, 0, 0, 0, 0};
        short8 zz  = {0, 0, 0, 0, 0, 0, 0, 0};
        *(short8*)(tb + 6 * 512 + l15 * 8) = env;             // kg = 0
        *(short8*)(tb + 6 * 512 + (16 + l15) * 8) = zz;       // kg = 1..3: zero
        *(short8*)(tb + 6 * 512 + (32 + l15) * 8) = zz;
        *(short8*)(tb + 6 * 512 + (48 + l15) * 8) = zz;
        en2h[k] = 0.5f * s;
    } else {
        const int p = (blockIdx.x - 64) * 128 + tid;
        const int b = p >> 10, hw = p & 1023;
        packed[p] = ~0ull;                    // re-init argmin cell every call
        float s = 0.f;
        #pragma unroll
        for (int c = 0; c < 8; ++c) {
            short8 h1v, h2v, h3v;
            #pragma unroll
            for (int j = 0; j < 8; ++j) {
                float v = x[(b * Dd + c * 8 + j) * 1024 + hw];
                s = fmaf(v, v, s);
                unsigned short h1, h2, h3; split3(-v, h1, h2, h3);   // negated
                h1v[j] = (short)h1; h2v[j] = (short)h2; h3v[j] = (short)h3;
            }
            *(short8*)(xs + (size_t)p * Dd + c * 8) = h1v;
            *(short8*)(xs + PLANE + (size_t)p * Dd + c * 8) = h2v;
            *(short8*)(xs + 2 * PLANE + (size_t)p * Dd + c * 8) = h3v;
        }
        xn2[p] = s;
    }
}

// one 16-codeword tile: 1 en-MFMA + 24 product MFMAs + argmin.
__device__ __forceinline__ void tile_compute(
    const short8 (&a)[2][3][2], const short8 a_ones, const short8 (&b)[7],
    int nb, int l15, float (&bv)[2][4], int (&bi)[2][4])
{
    const f32x4 zero = {0.f, 0.f, 0.f, 0.f};
    f32x4 acc_en = __builtin_amdgcn_mfma_f32_16x16x32_bf16(a_ones, b[6], zero, 0, 0, 0);
    f32x4 acc[2][2];
    acc[0][0] = acc_en; acc[1][0] = acc_en;
    acc[0][1] = zero;   acc[1][1] = zero;
    #define PROD(sx, se) \
        acc[0][0] = __builtin_amdgcn_mfma_f32_16x16x32_bf16(a[0][sx][0], b[(se)*2+0], acc[0][0], 0,0,0); \
        acc[1][0] = __builtin_amdgcn_mfma_f32_16x16x32_bf16(a[1][sx][0], b[(se)*2+0], acc[1][0], 0,0,0); \
        acc[0][1] = __builtin_amdgcn_mfma_f32_16x16x32_bf16(a[0][sx][1], b[(se)*2+1], acc[0][1], 0,0,0); \
        acc[1][1] = __builtin_amdgcn_mfma_f32_16x16x32_bf16(a[1][sx][1], b[(se)*2+1], acc[1][1], 0,0,0);
    PROD(0,0) PROD(0,1) PROD(1,0) PROD(0,2) PROD(1,1) PROD(2,0)
    #undef PROD
    #pragma unroll
    for (int mi = 0; mi < 2; ++mi)
        #pragma unroll
        for (int j = 0; j < 4; ++j) {
            float s = acc[mi][0][j] + acc[mi][1][j];   // en - x.e
            if (s < bv[mi][j]) { bv[mi][j] = s; bi[mi][j] = nb + l15; }
        }
}

// R12's converged dist schedule (51 us, 12-structure optimum — R15-benched
// version verbatim). Ascending-k visit order (first-occurrence ties); only
// the ds_reads are barrier-locked; vmcnt(4) = the 4 staging loads. Epilogue
// finishes the global argmin with packed (sortable-val, idx) u64 atomicMin.
// NOTE: do NOT set a tight min-waves hint (R6: VGPR capped to 48 -> spill).
// NOTE: no ring/setprio/in-lane-tiebreak (R16: each regressed, -29% combined).
__global__ __launch_bounds__(256, 2) void dist_mfma(
    const unsigned short* __restrict__ xs, const unsigned short* __restrict__ es_t,
    unsigned long long* __restrict__ packed)
{
    __shared__ __align__(16) unsigned short sB[2][2 * TILE_USH];  // 2 x 16 KB

    const int tid = threadIdx.x;
    const int w = tid >> 6, lane = tid & 63;
    const int l15 = lane & 15, kg = lane >> 4;
    const int m0 = blockIdx.x * 128 + w * 32;
    const int t0 = blockIdx.y * NT;
    const int pr0 = t0 / 2;

    short8 a[2][3][2];
    #pragma unroll
    for (int mi = 0; mi < 2; ++mi) {
        const unsigned short* xp = xs + (size_t)(m0 + mi * 16 + l15) * Dd + kg * 8;
        #pragma unroll
        for (int s = 0; s < 3; ++s)
            #pragma unroll
            for (int ks = 0; ks < 2; ++ks)
                a[mi][s][ks] = *(const short8*)(xp + s * PLANE + ks * 32);
    }
    const short8 a_ones = (kg == 0)
        ? short8{(short)0x3F80, (short)0x3F80, (short)0x3F80, 0, 0, 0, 0, 0}
        : short8{0, 0, 0, 0, 0, 0, 0, 0};

    float bv[2][4]; int bi[2][4];
    #pragma unroll
    for (int mi = 0; mi < 2; ++mi)
        #pragma unroll
        for (int j = 0; j < 4; ++j) { bv[mi][j] = FLT_MAX; bi[mi][j] = 0; }

    #define STAGE_PAIR(buf, pi) { \
        const char* gb_ = (const char*)es_t + (size_t)(pi) * PAIR_BYTES; \
        char* lb_ = (char*)&sB[buf][0]; \
        _Pragma("unroll") \
        for (int r_ = 0; r_ < 4; ++r_) { \
            const int off_ = r_ * 4096 + w * 1024; \
            gload_lds16(gb_ + off_ + lane * 16, lb_ + off_); } }

    STAGE_PAIR(0, pr0)
    asm volatile("s_waitcnt vmcnt(0)" ::: "memory");
    asm volatile("s_barrier" ::: "memory");

    #pragma unroll 1
    for (int pp = 0; pp < NPAIR; ++pp) {
        const int cur = pp & 1;
        const int pn = (pp + 1 < NPAIR) ? pp + 1 : NPAIR - 1;  // clamped: uniform count
        STAGE_PAIR(cur ^ 1, pr0 + pn)
        asm volatile("s_waitcnt vmcnt(4)" ::: "memory");   // pair pp staged
        asm volatile("s_barrier" ::: "memory");            // buf[cur] ready

        short8 bf0[7], bf1[7];
        const unsigned short* lb = &sB[cur][lane * 8];
        #pragma unroll
        for (int f = 0; f < 7; ++f) bf0[f] = *(const short8*)(lb + f * 512);
        #pragma unroll
        for (int f = 0; f < 7; ++f) bf1[f] = *(const short8*)(lb + TILE_USH + f * 512);
        asm volatile("s_waitcnt lgkmcnt(0)" ::: "memory");
        asm volatile("s_barrier" ::: "memory");            // buf[cur] free

        const int ti = t0 + pp * 2;
        tile_compute(a, a_ones, bf0, ti * 16, l15, bv, bi);
        tile_compute(a, a_ones, bf1, ti * 16 + 16, l15, bv, bi);
    }

    #pragma unroll
    for (int m = 1; m < 16; m <<= 1) {
        #pragma unroll
        for (int mi = 0; mi < 2; ++mi)
            #pragma unroll
            for (int j = 0; j < 4; ++j) {
                float ov = __shfl_xor(bv[mi][j], m, 64);
                int   oi = __shfl_xor(bi[mi][j], m, 64);
                if (ov < bv[mi][j] || (ov == bv[mi][j] && oi < bi[mi][j])) {
                    bv[mi][j] = ov; bi[mi][j] = oi;
                }
            }
    }
    if (l15 == 0) {
        #pragma unroll
        for (int mi = 0; mi < 2; ++mi)
            #pragma unroll
            for (int j = 0; j < 4; ++j) {
                int pix = m0 + mi * 16 + kg * 4 + j;
                unsigned long long pk =
                    ((unsigned long long)sortable(bv[mi][j]) << 32) | (unsigned)bi[mi][j];
                atomicMin(&packed[pix], pk);
            }
    }
}

// ---- apply: unpack winner, coefficients inline, stream qd/q; ind at y==0 ----
// grid (32, 8): 256 pixels per block, 8 d's per blockIdx.y
__global__ __launch_bounds__(256) void apply_kernel(
    const float* __restrict__ x, const float* __restrict__ et,
    const float* __restrict__ en2h, const float* __restrict__ xn2,
    const unsigned long long* __restrict__ packed,
    float* __restrict__ out_qd, float* __restrict__ out_q, float* __restrict__ out_ind)
{
    const int p = blockIdx.x * 256 + threadIdx.x;
    const unsigned long long pk = packed[p];
    const int bii = (int)(pk & 0xFFFFFFFFu);
    const float bvv = unsortable((unsigned)(pk >> 32));
    if (blockIdx.y == 0) out_ind[p] = (float)bii;

    float sx2 = xn2[p];
    float enh = en2h[bii];
    float sq2 = 2.f * enh;            // ||q||^2
    float sxq = enh - bvv;            // x.q recovered from winning score
    float ne = sqrtf(sx2), nq = sqrtf(sq2);
    float inv_e = 1.f / (ne + EPS), inv_q = 1.f / (nq + EPS);
    float lmbda = (nq + EPS) * inv_e;
    float ehat_dot_e = sx2 * inv_e;
    float rn2 = sx2 * inv_e * inv_e + 2.f * sxq * inv_e * inv_q + sq2 * inv_q * inv_q;
    float inv_r = rsqrtf(rn2);
    float rde = (sx2 * inv_e + sxq * inv_q) * inv_r;
    float cx = lmbda * (1.f - 2.f * rde * inv_r * inv_e);
    float cq = 2.f * lmbda * inv_q * (ehat_dot_e - rde * inv_r);

    const int b = p >> 10, hw = p & 1023;
    const int d0 = blockIdx.y * 8;
    const float* xb = x + (b * Dd + d0) * 1024 + hw;
    const float* er = et + (size_t)bii * Dd + d0;
    float* qd_b = out_qd + (b * Dd + d0) * 1024 + hw;
    float* q_b  = out_q  + (b * Dd + d0) * 1024 + hw;
    #pragma unroll
    for (int dv = 0; dv < 2; ++dv) {
        float4 q4 = *(const float4*)(er + dv * 4);
        #pragma unroll
        for (int jj = 0; jj < 4; ++jj) {
            int d = dv * 4 + jj;
            float xv = xb[d * 1024];
            float qv = ((const float*)&q4)[jj];
            qd_b[d * 1024] = cx * xv + cq * qv;
            q_b[d * 1024]  = qv;
        }
    }
}

extern "C" void kernel_launch(void* const* d_in, const int* in_sizes, int n_in,
                              void* d_out, int out_size, void* d_ws, size_t ws_size,
                              hipStream_t stream) {
    const float* x = (const float*)d_in[0];   // (8,64,32,32)
    const float* e = (const float*)d_in[1];   // (64,8192)
    float* out = (float*)d_out;
    float* out_qd  = out;
    float* out_q   = out + Nn * Dd;
    float* out_ind = out + 2 * Nn * Dd;

    unsigned short* xs   = (unsigned short*)d_ws;          // 3*PLANE ushort (3 MB)
    unsigned short* es_t = xs + 3 * PLANE;                 // 512*4096 ushort (4 MB)
    float* et   = (float*)(es_t + (size_t)(Kk / 16) * TILE_USH);  // Kk*Dd f32 (2 MB)
    float* en2h = et + (size_t)Kk * Dd;                    // Kk f32
    float* xn2  = en2h + Kk;                               // Nn f32
    unsigned long long* packed = (unsigned long long*)(xn2 + Nn);  // Nn u64 (64 KB)

    prep_kernel<<<128, 128, 0, stream>>>(e, x, es_t, en2h, et, xs, xn2, packed);
    dist_mfma<<<dim3(Nn / 128, KSPLIT), 256, 0, stream>>>(xs, es_t, packed);
    apply_kernel<<<dim3(Nn / 256, 8), 256, 0, stream>>>(x, et, en2h, xn2, packed,
                                                        out_qd, out_q, out_ind);
}